// Round 7
// baseline (813.015 us; speedup 1.0000x reference)
//
#include <hip/hip_runtime.h>
#include <hip/hip_bf16.h>
#include <math.h>

// Problem constants (B=64, S=512, D=256, L=3)
#define D_HID 256
#define N_B   64
#define S_LEN 512
#define N_L   3
#define M_ROWS (N_B * S_LEN)   // 32768 rows

typedef __bf16 bf16_t;
typedef __bf16 bf16x8 __attribute__((ext_vector_type(8)));
typedef __bf16 bf16x4 __attribute__((ext_vector_type(4)));
typedef float  f32x4  __attribute__((ext_vector_type(4)));
typedef unsigned int u32;

__device__ __forceinline__ f32x4 mfma16(bf16x8 a, bf16x8 b, f32x4 c) {
    return __builtin_amdgcn_mfma_f32_16x16x32_bf16(a, b, c, 0, 0, 0);
}

// async global->LDS, 16B per lane; LDS dest = wave-uniform base + lane*16
__device__ __forceinline__ void gld_lds16(const void* g, void* l) {
    __builtin_amdgcn_global_load_lds((const __attribute__((address_space(1))) u32*)g,
                                     (__attribute__((address_space(3))) u32*)l, 16, 0, 0);
}

__device__ __forceinline__ u32 pk_bf16(float a, float b) {
    return (u32)(__hip_bfloat16_raw(__hip_bfloat16(a)).x) |
           ((u32)(__hip_bfloat16_raw(__hip_bfloat16(b)).x) << 16);
}

// ---------------------------------------------------------------------------
// All-in-one weight transpose + bf16: 6 tensors, grid (768, 6).
// ---------------------------------------------------------------------------
__global__ __launch_bounds__(256) void transpose_all(const float* __restrict__ wq,
                                                     const float* __restrict__ wk,
                                                     const float* __restrict__ wv,
                                                     const float* __restrict__ wo,
                                                     const float* __restrict__ w1,
                                                     const float* __restrict__ w2,
                                                     bf16_t* __restrict__ Wqkv,
                                                     bf16_t* __restrict__ Wrest) {
    const int t = blockIdx.y;
    const float* src = t == 0 ? wq : t == 1 ? wk : t == 2 ? wv
                     : t == 3 ? wo : t == 4 ? w1 : w2;
    const int i = blockIdx.x * 256 + threadIdx.x;   // [0, 196608)
    const int k = i & 255;
    const int n = (i >> 8) & 255;
    const int l = i >> 16;
    const bf16_t v = (bf16_t)src[((size_t)l << 16) + ((size_t)k << 8) + n];
    if (t < 3) Wqkv[(size_t)l * 3 * 65536 + t * 65536 + n * 256 + k] = v;
    else       Wrest[(size_t)(t - 3) * 196608 + l * 65536 + n * 256 + k] = v;
}

// ---------------------------------------------------------------------------
// LayerNorm: Hb = bf16( LN(in)*g + b ). One wave per row.
// ---------------------------------------------------------------------------
__global__ __launch_bounds__(256) void ln_fwd(const float* __restrict__ in,
                                              const float* __restrict__ g,
                                              const float* __restrict__ b,
                                              bf16_t* __restrict__ Hb) {
    int row  = blockIdx.x * 4 + (threadIdx.x >> 6);
    int lane = threadIdx.x & 63;
    float4 x = ((const float4*)(in + (size_t)row * D_HID))[lane];
    float s  = x.x + x.y + x.z + x.w;
    float sq = x.x * x.x + x.y * x.y + x.z * x.z + x.w * x.w;
#pragma unroll
    for (int o = 1; o < 64; o <<= 1) { s += __shfl_xor(s, o); sq += __shfl_xor(sq, o); }
    float mean = s * (1.f / D_HID);
    float rstd = rsqrtf(sq * (1.f / D_HID) - mean * mean + 1e-5f);
    float4 gv = ((const float4*)g)[lane];
    float4 bv = ((const float4*)b)[lane];
    bf16x4 hb = { (bf16_t)((x.x - mean) * rstd * gv.x + bv.x),
                  (bf16_t)((x.y - mean) * rstd * gv.y + bv.y),
                  (bf16_t)((x.z - mean) * rstd * gv.z + bv.z),
                  (bf16_t)((x.w - mean) * rstd * gv.w + bv.w) };
    *((bf16x4*)(Hb + (size_t)row * D_HID) + lane) = hb;
}

// ---------------------------------------------------------------------------
// Fused: X = Hb + LN(T)*g + b ; Cb = bf16( LN(X)*cg + cb ). One wave per row.
// ---------------------------------------------------------------------------
__global__ __launch_bounds__(256) void ln_res_ln(const float* __restrict__ T,
                                                 const bf16_t* __restrict__ Hb,
                                                 const float* __restrict__ g,
                                                 const float* __restrict__ b,
                                                 const float* __restrict__ cg,
                                                 const float* __restrict__ cb,
                                                 float* __restrict__ X,
                                                 bf16_t* __restrict__ Cb) {
    int row  = blockIdx.x * 4 + (threadIdx.x >> 6);
    int lane = threadIdx.x & 63;
    float4 t = ((const float4*)(T + (size_t)row * D_HID))[lane];
    float s  = t.x + t.y + t.z + t.w;
    float sq = t.x * t.x + t.y * t.y + t.z * t.z + t.w * t.w;
#pragma unroll
    for (int o = 1; o < 64; o <<= 1) { s += __shfl_xor(s, o); sq += __shfl_xor(sq, o); }
    float mean = s * (1.f / D_HID);
    float rstd = rsqrtf(sq * (1.f / D_HID) - mean * mean + 1e-5f);
    float4 gv = ((const float4*)g)[lane];
    float4 bv = ((const float4*)b)[lane];
    bf16x4 hb = *((const bf16x4*)(Hb + (size_t)row * D_HID) + lane);
    float4 x;
    x.x = (float)hb[0] + (t.x - mean) * rstd * gv.x + bv.x;
    x.y = (float)hb[1] + (t.y - mean) * rstd * gv.y + bv.y;
    x.z = (float)hb[2] + (t.z - mean) * rstd * gv.z + bv.z;
    x.w = (float)hb[3] + (t.w - mean) * rstd * gv.w + bv.w;
    ((float4*)(X + (size_t)row * D_HID))[lane] = x;
    // second LN
    float s2  = x.x + x.y + x.z + x.w;
    float sq2 = x.x * x.x + x.y * x.y + x.z * x.z + x.w * x.w;
#pragma unroll
    for (int o = 1; o < 64; o <<= 1) { s2 += __shfl_xor(s2, o); sq2 += __shfl_xor(sq2, o); }
    float mean2 = s2 * (1.f / D_HID);
    float rstd2 = rsqrtf(sq2 * (1.f / D_HID) - mean2 * mean2 + 1e-5f);
    float4 cgv = ((const float4*)cg)[lane];
    float4 cbv = ((const float4*)cb)[lane];
    bf16x4 c = { (bf16_t)((x.x - mean2) * rstd2 * cgv.x + cbv.x),
                 (bf16_t)((x.y - mean2) * rstd2 * cgv.y + cbv.y),
                 (bf16_t)((x.z - mean2) * rstd2 * cgv.z + cbv.z),
                 (bf16_t)((x.w - mean2) * rstd2 * cgv.w + cbv.w) };
    *((bf16x4*)(Cb + (size_t)row * D_HID) + lane) = c;
}

// ---------------------------------------------------------------------------
// GEMM core v3: 64x128 tile, BK=64, 2-phase double-buffered LDS pipeline.
// LDS 48KB -> 3 blocks/CU resident; cross-block overlap hides stage drains.
// XOR swizzle: linear LDS dest + inverse-permuted global source + XOR read.
// 4 waves (2 wm x 2 wn); wave tile 32x64, acc[2][4].
// ---------------------------------------------------------------------------
__device__ __forceinline__ void stage_tile(const bf16_t* __restrict__ A,
                                           const bf16_t* __restrict__ W,
                                           int m0, int n0, int kt,
                                           bf16_t* As, bf16_t* Bs) {
    const int lane = threadIdx.x & 63;
    const int wid  = threadIdx.x >> 6;
#pragma unroll
    for (int i = 0; i < 2; ++i) {                       // A: 64 rows x 64 k
        const int base8 = i * 256 + wid * 64;
        const int idx8  = base8 + lane;
        const int row   = idx8 >> 3;
        const int sc8   = (idx8 & 7) ^ (row & 7);
        gld_lds16(A + (size_t)(m0 + row) * D_HID + kt * 64 + sc8 * 8, As + base8 * 8);
    }
#pragma unroll
    for (int i = 0; i < 4; ++i) {                       // B: 128 rows x 64 k
        const int base8 = i * 256 + wid * 64;
        const int idx8  = base8 + lane;
        const int row   = idx8 >> 3;
        const int sc8   = (idx8 & 7) ^ (row & 7);
        gld_lds16(W + (size_t)(n0 + row) * D_HID + kt * 64 + sc8 * 8, Bs + base8 * 8);
    }
}

__device__ __forceinline__ void compute_tile(const bf16_t* As, const bf16_t* Bs,
                                             f32x4 (&acc)[2][4]) {
    const int lane = threadIdx.x & 63;
    const int wid  = threadIdx.x >> 6;
    const int wm = wid >> 1, wn = wid & 1;
    const int r = lane & 15, g = lane >> 4;
#pragma unroll
    for (int ks = 0; ks < 2; ++ks) {
        bf16x8 af[2], bfr[4];
#pragma unroll
        for (int mt = 0; mt < 2; ++mt) {
            const int row = wm * 32 + mt * 16 + r;
            const int c8  = (ks * 4 + g) ^ (row & 7);
            af[mt] = *(const bf16x8*)(As + row * 64 + c8 * 8);
        }
#pragma unroll
        for (int nt = 0; nt < 4; ++nt) {
            const int row = wn * 64 + nt * 16 + r;
            const int c8  = (ks * 4 + g) ^ (row & 7);
            bfr[nt] = *(const bf16x8*)(Bs + row * 64 + c8 * 8);
        }
#pragma unroll
        for (int mt = 0; mt < 2; ++mt)
#pragma unroll
            for (int nt = 0; nt < 4; ++nt)
                acc[mt][nt] = mfma16(af[mt], bfr[nt], acc[mt][nt]);
    }
}

__device__ __forceinline__ void gemm_core(const bf16_t* __restrict__ A,
                                          const bf16_t* __restrict__ W,
                                          int m0, int n0,
                                          bf16_t (&As)[2][4096], bf16_t (&Bs)[2][8192],
                                          f32x4 (&acc)[2][4]) {
    stage_tile(A, W, m0, n0, 0, As[0], Bs[0]);
    asm volatile("s_waitcnt vmcnt(0)" ::: "memory");
    __builtin_amdgcn_s_barrier();
#pragma unroll
    for (int kt = 0; kt < 4; ++kt) {
        const int cur = kt & 1;
        if (kt < 3) stage_tile(A, W, m0, n0, kt + 1, As[cur ^ 1], Bs[cur ^ 1]);
        compute_tile(As[cur], Bs[cur], acc);
        if (kt < 3) {
            asm volatile("s_waitcnt vmcnt(0)" ::: "memory");
            __builtin_amdgcn_s_barrier();
        }
    }
}

// Fused QKV GEMM: Wp packed [768][256]. Grid (M/64, 6).
__global__ __launch_bounds__(256) void gemm_qkv(const bf16_t* __restrict__ A,
                                                const bf16_t* __restrict__ Wp,
                                                const float* __restrict__ bq,
                                                const float* __restrict__ bk,
                                                const float* __restrict__ bv,
                                                bf16_t* __restrict__ Qb,
                                                bf16_t* __restrict__ Kb,
                                                bf16_t* __restrict__ Vt) {
    __shared__ bf16_t As[2][4096], Bs[2][8192];
    f32x4 acc[2][4] = {};
    const int m0 = blockIdx.x * 64, n0 = blockIdx.y * 128;
    gemm_core(A, Wp, m0, n0, As, Bs, acc);
    const int lane = threadIdx.x & 63, wid = threadIdx.x >> 6;
    const int wm = wid >> 1, wn = wid & 1, r = lane & 15, g = lane >> 4;
#pragma unroll
    for (int nt = 0; nt < 4; ++nt) {
        const int col = n0 + wn * 64 + nt * 16 + r;
        const int t = col >> 8, cc = col & 255;
        const float bias = (t == 0 ? bq : t == 1 ? bk : bv)[cc];
#pragma unroll
        for (int mt = 0; mt < 2; ++mt)
#pragma unroll
            for (int rr = 0; rr < 4; ++rr) {
                const int row = m0 + wm * 32 + mt * 16 + g * 4 + rr;
                const float v = acc[mt][nt][rr] + bias;
                if (t == 0)      Qb[(size_t)row * D_HID + cc] = (bf16_t)v;
                else if (t == 1) Kb[(size_t)row * D_HID + cc] = (bf16_t)v;
                else             Vt[((size_t)(row >> 9) * D_HID + cc) * S_LEN + (row & 511)] = (bf16_t)v;
            }
    }
}

// Generic GEMM, N=256. EPI 1: gelu->bf16  2: f32  3: addsrc+ -> f32
template <int EPI>
__global__ __launch_bounds__(256) void gemm_one(const bf16_t* __restrict__ A,
                                                const bf16_t* __restrict__ W,
                                                const float* __restrict__ bias,
                                                void* __restrict__ outp,
                                                const float* __restrict__ addsrc) {
    __shared__ bf16_t As[2][4096], Bs[2][8192];
    f32x4 acc[2][4] = {};
    const int m0 = blockIdx.x * 64, n0 = blockIdx.y * 128;
    gemm_core(A, W, m0, n0, As, Bs, acc);
    const int lane = threadIdx.x & 63, wid = threadIdx.x >> 6;
    const int wm = wid >> 1, wn = wid & 1, r = lane & 15, g = lane >> 4;
#pragma unroll
    for (int nt = 0; nt < 4; ++nt) {
        const int col = n0 + wn * 64 + nt * 16 + r;
        const float bv = bias[col];
#pragma unroll
        for (int mt = 0; mt < 2; ++mt)
#pragma unroll
            for (int rr = 0; rr < 4; ++rr) {
                const size_t idx = (size_t)(m0 + wm * 32 + mt * 16 + g * 4 + rr) * D_HID + col;
                float v = acc[mt][nt][rr] + bv;
                if constexpr (EPI == 1) {
                    v = 0.5f * v * (1.f + erff(v * 0.70710678118654752f));
                    ((bf16_t*)outp)[idx] = (bf16_t)v;
                } else if constexpr (EPI == 2) {
                    ((float*)outp)[idx] = v;
                } else {
                    ((float*)outp)[idx] = addsrc[idx] + v;
                }
            }
    }
}

// ---------------------------------------------------------------------------
// Flash attention v6. QBLK=16: grid 2048 (XCD-chunked, 8 blocks/CU), 4 waves.
// Per-block state halved vs v5 -> high occupancy; barriers overlap across
// blocks. Swapped QK^T; P in swizzled LDS; V contiguous from Vt[b][d][s].
// ---------------------------------------------------------------------------
__global__ __launch_bounds__(256, 2) void attn_fwd(const bf16_t* __restrict__ Q,
                                                   const bf16_t* __restrict__ K,
                                                   const bf16_t* __restrict__ Vt,
                                                   const float* __restrict__ btab,
                                                   const int* __restrict__ mask,
                                                   bf16_t* __restrict__ AO) {
    __shared__ float  bias_lds[1024];
    __shared__ float  mask_add[512];
    __shared__ bf16_t P_lds[16 * 64];        // 2KB, row stride 128B, XOR-swizzled
    __shared__ float  m_part[4][16], l_part[4][16];
    __shared__ bf16_t o_lds[16][264];        // 8.25KB

    const int tid = threadIdx.x, lane = tid & 63, w = tid >> 6;
    const int r = lane & 15, g = lane >> 4;

    // XCD-chunked mapping: 8 batches per XCD -> K/V L2-resident
    const int lid = blockIdx.x;
    const int xcd = lid & 7, slot = lid >> 3;          // slot 0..255
    const int b  = xcd * 8 + (slot >> 5);
    const int q0 = (slot & 31) * 16;

    for (int i = tid; i < 1024; i += 256) {
        const int rel = i - 512;
        const int bucket = (rel < 0) ? (511 - rel) : rel;
        bias_lds[i] = btab[bucket];
    }
    for (int i = tid; i < 512; i += 256)
        mask_add[i] = mask[b * S_LEN + i] ? 0.f : -3.0e38f;
    __syncthreads();

    const bf16_t* Qp = Q  + ((size_t)b * S_LEN + q0) * D_HID;
    const bf16_t* Kp = K  + (size_t)b * S_LEN * D_HID;
    const bf16_t* Vp = Vt + (size_t)b * D_HID * S_LEN;

    // Q-hoist: 16 rows, all K-slices (32 VGPR)
    bf16x8 qf[8];
#pragma unroll
    for (int ks = 0; ks < 8; ++ks)
        qf[ks] = *(const bf16x8*)(Qp + (size_t)r * D_HID + ks * 32 + g * 8);

    f32x4 oacc[4] = {};                      // d-16-blocks within wave's 64 d
    float m_run = -3.0e38f, l_run = 0.f;

#pragma unroll 1
    for (int kt = 0; kt < 8; ++kt) {
        const int k0 = kt * 64;
        // V-prefetch for this tile (consumed after B2)
        bf16x8 vpre[2][4];
#pragma unroll
        for (int ks = 0; ks < 2; ++ks)
#pragma unroll
            for (int nt = 0; nt < 4; ++nt)
                vpre[ks][nt] = *(const bf16x8*)(Vp + (size_t)(w * 64 + nt * 16 + r) * S_LEN
                                                     + k0 + ks * 32 + g * 8);
        // QK^T swapped: lane holds S^T[k = k0+w*16+g*4+rr][q = q0+r]
        f32x4 sacc = {};
#pragma unroll
        for (int ks = 0; ks < 8; ++ks) {
            bf16x8 kf = *(const bf16x8*)(Kp + (size_t)(k0 + w * 16 + r) * D_HID + ks * 32 + g * 8);
            sacc = mfma16(kf, qf[ks], sacc);
        }
        // bias + mask + per-wave max
        float mx = -3.0e38f;
        const int qg = q0 + r;
#pragma unroll
        for (int rr = 0; rr < 4; ++rr) {
            const int kg = k0 + w * 16 + g * 4 + rr;
            float ev = sacc[rr] * 0.0625f + bias_lds[kg - qg + 512] + mask_add[kg];
            sacc[rr] = ev;
            mx = fmaxf(mx, ev);
        }
        mx = fmaxf(mx, __shfl_xor(mx, 16));
        mx = fmaxf(mx, __shfl_xor(mx, 32));
        if (g == 0) m_part[w][r] = mx;
        __syncthreads();                                   // B1
        const float tm = fmaxf(fmaxf(m_part[0][r], m_part[1][r]),
                               fmaxf(m_part[2][r], m_part[3][r]));
        const float mnew = fmaxf(m_run, tm);
        const float fac  = __expf(m_run - mnew);
        m_run = mnew;
        // P = exp(ev - m), l-partials, pack bf16 -> swizzled LDS
        const float p0 = __expf(sacc[0] - mnew);
        const float p1 = __expf(sacc[1] - mnew);
        const float p2 = __expf(sacc[2] - mnew);
        const float p3 = __expf(sacc[3] - mnew);
        float ls = p0 + p1 + p2 + p3;
        ls += __shfl_xor(ls, 16);
        ls += __shfl_xor(ls, 32);
        if (g == 0) l_part[w][r] = ls;
        {
            const int u = (2 * w + (g >> 1)) ^ (r & 7);    // 16B-unit XOR swizzle
            uint2 pv; pv.x = pk_bf16(p0, p1); pv.y = pk_bf16(p2, p3);
            *(uint2*)((char*)P_lds + r * 128 + u * 16 + (g & 1) * 8) = pv;
        }
        __syncthreads();                                   // B2
        // l update + O rescale
        const float lt = l_part[0][r] + l_part[1][r] + l_part[2][r] + l_part[3][r];
        l_run = l_run * fac + lt;
#pragma unroll
        for (int nt = 0; nt < 4; ++nt)
#pragma unroll
            for (int rr = 0; rr < 4; ++rr)
                oacc[nt][rr] *= fac;
        // PV (O^T): A = prefetched V regs, B = P rows (swizzled LDS)
#pragma unroll
        for (int ks = 0; ks < 2; ++ks) {
            const int u = (ks * 4 + g) ^ (r & 7);
            bf16x8 pf = *(const bf16x8*)((const char*)P_lds + r * 128 + u * 16);
            __builtin_amdgcn_s_setprio(1);
#pragma unroll
            for (int nt = 0; nt < 4; ++nt)
                oacc[nt] = mfma16(vpre[ks][nt], pf, oacc[nt]);
            __builtin_amdgcn_s_setprio(0);
        }
    }
    // epilogue: scale 1/l, transpose via LDS, store
    const float inv_l = 1.f / fmaxf(l_run, 1e-30f);
#pragma unroll
    for (int nt = 0; nt < 4; ++nt) {
        const int d = w * 64 + nt * 16 + g * 4;
        bf16x4 ob = { (bf16_t)(oacc[nt][0] * inv_l),
                      (bf16_t)(oacc[nt][1] * inv_l),
                      (bf16_t)(oacc[nt][2] * inv_l),
                      (bf16_t)(oacc[nt][3] * inv_l) };
        *(bf16x4*)&o_lds[r][d] = ob;
    }
    __syncthreads();
    bf16_t* Op = AO + ((size_t)b * S_LEN + q0) * D_HID;
#pragma unroll
    for (int it = 0; it < 2; ++it) {
        const int idx = it * 256 + tid;      // 512 units = 16 rows x 32 x 16B
        const int row = idx >> 5, u = idx & 31;
        bf16x8 vv = *(const bf16x8*)&o_lds[row][u * 8];
        *(bf16x8*)(Op + (size_t)row * D_HID + u * 8) = vv;
    }
}

// ---------------------------------------------------------------------------
extern "C" void kernel_launch(void* const* d_in, const int* in_sizes, int n_in,
                              void* d_out, int out_size, void* d_ws, size_t ws_size,
                              hipStream_t stream) {
    const float* x_in = (const float*)d_in[0];
    const int*   mask = (const int*)d_in[1];
    const float* btab = (const float*)d_in[2];
    const float* ln_g = (const float*)d_in[3];
    const float* ln_b = (const float*)d_in[4];
    const float* wq = (const float*)d_in[5];
    const float* bq = (const float*)d_in[6];
    const float* wk = (const float*)d_in[7];
    const float* bk = (const float*)d_in[8];
    const float* wv = (const float*)d_in[9];
    const float* bv = (const float*)d_in[10];
    const float* wo = (const float*)d_in[11];
    const float* bo = (const float*)d_in[12];
    const float* cg = (const float*)d_in[13];
    const float* cb = (const float*)d_in[14];
    const float* w1 = (const float*)d_in[15];
    const float* b1 = (const float*)d_in[16];
    const float* w2 = (const float*)d_in[17];
    const float* b2 = (const float*)d_in[18];
    float* out = (float*)d_out;

    // Workspace layout (~120 MB). AO is its OWN region (round-6 bug: AO
    // aliased Hb while Hb was needed for the residual).
    char* p = (char*)d_ws;
    const size_t F32SZ  = (size_t)M_ROWS * D_HID * sizeof(float);   // 33.5 MB
    const size_t BF16SZ = (size_t)M_ROWS * D_HID * sizeof(bf16_t);  // 16.8 MB
    float*  X  = (float*)p;  p += F32SZ;
    bf16_t* Hb = (bf16_t*)p; p += BF16SZ;   // residual h (bf16), live thru ln_res_ln
    bf16_t* Qb = (bf16_t*)p; p += BF16SZ;   // later: Cb
    bf16_t* Kb = (bf16_t*)p;                // T (f32) spans Kb+Vt; T1b reuses Kb
    float*  T  = (float*)Kb;
    bf16_t* T1b = Kb;
    p += BF16SZ;
    bf16_t* Vt = (bf16_t*)p; p += BF16SZ;   // transposed V [b][d][s]
    bf16_t* AO = (bf16_t*)p; p += BF16SZ;   // attention output (separate!)
    bf16_t* Wqkv = (bf16_t*)p; p += (size_t)N_L * 768 * 256 * sizeof(bf16_t);  // packed
    bf16_t* Wrest = (bf16_t*)p;             // Wo,W1,W2: 3 * L * 65536 bf16
    bf16_t* Cb = Qb;

    transpose_all<<<dim3(768, 6), dim3(256), 0, stream>>>(wq, wk, wv, wo, w1, w2, Wqkv, Wrest);

    const dim3 gblk(256, 1, 1);
    const dim3 grid_qkv(M_ROWS / 64, 6, 1);
    const dim3 grid_one(M_ROWS / 64, 2, 1);

    for (int j = 0; j < N_L; ++j) {
        const bf16_t* WQKVj = Wqkv + (size_t)j * 3 * 65536;
        const bf16_t* WOt = Wrest + ((size_t)0 * N_L + j) * 65536;
        const bf16_t* W1t = Wrest + ((size_t)1 * N_L + j) * 65536;
        const bf16_t* W2t = Wrest + ((size_t)2 * N_L + j) * 65536;

        ln_fwd<<<dim3(M_ROWS / 4), gblk, 0, stream>>>(j == 0 ? x_in : X,
                                                      ln_g + j * D_HID, ln_b + j * D_HID, Hb);
        gemm_qkv<<<grid_qkv, gblk, 0, stream>>>(Hb, WQKVj, bq + j * D_HID, bk + j * D_HID,
                                                bv + j * D_HID, Qb, Kb, Vt);
        attn_fwd<<<dim3(N_B * 32, 1, 1), gblk, 0, stream>>>(Qb, Kb, Vt, btab, mask, AO);
        gemm_one<2><<<grid_one, gblk, 0, stream>>>(AO, WOt, bo + j * D_HID, T, nullptr);
        ln_res_ln<<<dim3(M_ROWS / 4), gblk, 0, stream>>>(T, Hb, ln_g + j * D_HID, ln_b + j * D_HID,
                                                         cg + j * D_HID, cb + j * D_HID, X, Cb);
        gemm_one<1><<<grid_one, gblk, 0, stream>>>(Cb, W1t, b1 + j * D_HID, T1b, nullptr);
        gemm_one<3><<<grid_one, gblk, 0, stream>>>(T1b, W2t, b2 + j * D_HID,
                                                   (j == N_L - 1) ? (void*)out : (void*)X, X);
    }
}

// Round 8
// 808.889 us; speedup vs baseline: 1.0051x; 1.0051x over previous
//
#include <hip/hip_runtime.h>
#include <hip/hip_bf16.h>
#include <math.h>

// Problem constants (B=64, S=512, D=256, L=3)
#define D_HID 256
#define N_B   64
#define S_LEN 512
#define N_L   3
#define M_ROWS (N_B * S_LEN)   // 32768 rows

typedef __bf16 bf16_t;
typedef __bf16 bf16x8 __attribute__((ext_vector_type(8)));
typedef __bf16 bf16x4 __attribute__((ext_vector_type(4)));
typedef float  f32x4  __attribute__((ext_vector_type(4)));
typedef unsigned int u32;

__device__ __forceinline__ f32x4 mfma16(bf16x8 a, bf16x8 b, f32x4 c) {
    return __builtin_amdgcn_mfma_f32_16x16x32_bf16(a, b, c, 0, 0, 0);
}

// async global->LDS, 16B per lane; LDS dest = wave-uniform base + lane*16
__device__ __forceinline__ void gld_lds16(const void* g, void* l) {
    __builtin_amdgcn_global_load_lds((const __attribute__((address_space(1))) u32*)g,
                                     (__attribute__((address_space(3))) u32*)l, 16, 0, 0);
}

__device__ __forceinline__ u32 pk_bf16(float a, float b) {
    return (u32)(__hip_bfloat16_raw(__hip_bfloat16(a)).x) |
           ((u32)(__hip_bfloat16_raw(__hip_bfloat16(b)).x) << 16);
}

// ---------------------------------------------------------------------------
// All-in-one weight transpose + bf16: 6 tensors, grid (768, 6).
// ---------------------------------------------------------------------------
__global__ __launch_bounds__(256) void transpose_all(const float* __restrict__ wq,
                                                     const float* __restrict__ wk,
                                                     const float* __restrict__ wv,
                                                     const float* __restrict__ wo,
                                                     const float* __restrict__ w1,
                                                     const float* __restrict__ w2,
                                                     bf16_t* __restrict__ Wqkv,
                                                     bf16_t* __restrict__ Wrest) {
    const int t = blockIdx.y;
    const float* src = t == 0 ? wq : t == 1 ? wk : t == 2 ? wv
                     : t == 3 ? wo : t == 4 ? w1 : w2;
    const int i = blockIdx.x * 256 + threadIdx.x;   // [0, 196608)
    const int k = i & 255;
    const int n = (i >> 8) & 255;
    const int l = i >> 16;
    const bf16_t v = (bf16_t)src[((size_t)l << 16) + ((size_t)k << 8) + n];
    if (t < 3) Wqkv[(size_t)l * 3 * 65536 + t * 65536 + n * 256 + k] = v;
    else       Wrest[(size_t)(t - 3) * 196608 + l * 65536 + n * 256 + k] = v;
}

// ---------------------------------------------------------------------------
// LayerNorm: Hb = bf16( LN(in)*g + b ). One wave per row.
// ---------------------------------------------------------------------------
__global__ __launch_bounds__(256) void ln_fwd(const float* __restrict__ in,
                                              const float* __restrict__ g,
                                              const float* __restrict__ b,
                                              bf16_t* __restrict__ Hb) {
    int row  = blockIdx.x * 4 + (threadIdx.x >> 6);
    int lane = threadIdx.x & 63;
    float4 x = ((const float4*)(in + (size_t)row * D_HID))[lane];
    float s  = x.x + x.y + x.z + x.w;
    float sq = x.x * x.x + x.y * x.y + x.z * x.z + x.w * x.w;
#pragma unroll
    for (int o = 1; o < 64; o <<= 1) { s += __shfl_xor(s, o); sq += __shfl_xor(sq, o); }
    float mean = s * (1.f / D_HID);
    float rstd = rsqrtf(sq * (1.f / D_HID) - mean * mean + 1e-5f);
    float4 gv = ((const float4*)g)[lane];
    float4 bv = ((const float4*)b)[lane];
    bf16x4 hb = { (bf16_t)((x.x - mean) * rstd * gv.x + bv.x),
                  (bf16_t)((x.y - mean) * rstd * gv.y + bv.y),
                  (bf16_t)((x.z - mean) * rstd * gv.z + bv.z),
                  (bf16_t)((x.w - mean) * rstd * gv.w + bv.w) };
    *((bf16x4*)(Hb + (size_t)row * D_HID) + lane) = hb;
}

// ---------------------------------------------------------------------------
// Fused: X = Hb + LN(T)*g + b ; Cb = bf16( LN(X)*cg + cb ). One wave per row.
// ---------------------------------------------------------------------------
__global__ __launch_bounds__(256) void ln_res_ln(const float* __restrict__ T,
                                                 const bf16_t* __restrict__ Hb,
                                                 const float* __restrict__ g,
                                                 const float* __restrict__ b,
                                                 const float* __restrict__ cg,
                                                 const float* __restrict__ cb,
                                                 float* __restrict__ X,
                                                 bf16_t* __restrict__ Cb) {
    int row  = blockIdx.x * 4 + (threadIdx.x >> 6);
    int lane = threadIdx.x & 63;
    float4 t = ((const float4*)(T + (size_t)row * D_HID))[lane];
    float s  = t.x + t.y + t.z + t.w;
    float sq = t.x * t.x + t.y * t.y + t.z * t.z + t.w * t.w;
#pragma unroll
    for (int o = 1; o < 64; o <<= 1) { s += __shfl_xor(s, o); sq += __shfl_xor(sq, o); }
    float mean = s * (1.f / D_HID);
    float rstd = rsqrtf(sq * (1.f / D_HID) - mean * mean + 1e-5f);
    float4 gv = ((const float4*)g)[lane];
    float4 bv = ((const float4*)b)[lane];
    bf16x4 hb = *((const bf16x4*)(Hb + (size_t)row * D_HID) + lane);
    float4 x;
    x.x = (float)hb[0] + (t.x - mean) * rstd * gv.x + bv.x;
    x.y = (float)hb[1] + (t.y - mean) * rstd * gv.y + bv.y;
    x.z = (float)hb[2] + (t.z - mean) * rstd * gv.z + bv.z;
    x.w = (float)hb[3] + (t.w - mean) * rstd * gv.w + bv.w;
    ((float4*)(X + (size_t)row * D_HID))[lane] = x;
    // second LN
    float s2  = x.x + x.y + x.z + x.w;
    float sq2 = x.x * x.x + x.y * x.y + x.z * x.z + x.w * x.w;
#pragma unroll
    for (int o = 1; o < 64; o <<= 1) { s2 += __shfl_xor(s2, o); sq2 += __shfl_xor(sq2, o); }
    float mean2 = s2 * (1.f / D_HID);
    float rstd2 = rsqrtf(sq2 * (1.f / D_HID) - mean2 * mean2 + 1e-5f);
    float4 cgv = ((const float4*)cg)[lane];
    float4 cbv = ((const float4*)cb)[lane];
    bf16x4 c = { (bf16_t)((x.x - mean2) * rstd2 * cgv.x + cbv.x),
                 (bf16_t)((x.y - mean2) * rstd2 * cgv.y + cbv.y),
                 (bf16_t)((x.z - mean2) * rstd2 * cgv.z + cbv.z),
                 (bf16_t)((x.w - mean2) * rstd2 * cgv.w + cbv.w) };
    *((bf16x4*)(Cb + (size_t)row * D_HID) + lane) = c;
}

// ---------------------------------------------------------------------------
// GEMM core: 64x128 tile, BK=64, 2-phase double-buffered LDS pipeline.
// XOR swizzle: linear LDS dest + inverse-permuted global source + XOR read.
// ---------------------------------------------------------------------------
__device__ __forceinline__ void stage_tile(const bf16_t* __restrict__ A,
                                           const bf16_t* __restrict__ W,
                                           int m0, int n0, int kt,
                                           bf16_t* As, bf16_t* Bs) {
    const int lane = threadIdx.x & 63;
    const int wid  = threadIdx.x >> 6;
#pragma unroll
    for (int i = 0; i < 2; ++i) {                       // A: 64 rows x 64 k
        const int base8 = i * 256 + wid * 64;
        const int idx8  = base8 + lane;
        const int row   = idx8 >> 3;
        const int sc8   = (idx8 & 7) ^ (row & 7);
        gld_lds16(A + (size_t)(m0 + row) * D_HID + kt * 64 + sc8 * 8, As + base8 * 8);
    }
#pragma unroll
    for (int i = 0; i < 4; ++i) {                       // B: 128 rows x 64 k
        const int base8 = i * 256 + wid * 64;
        const int idx8  = base8 + lane;
        const int row   = idx8 >> 3;
        const int sc8   = (idx8 & 7) ^ (row & 7);
        gld_lds16(W + (size_t)(n0 + row) * D_HID + kt * 64 + sc8 * 8, Bs + base8 * 8);
    }
}

__device__ __forceinline__ void compute_tile(const bf16_t* As, const bf16_t* Bs,
                                             f32x4 (&acc)[2][4]) {
    const int lane = threadIdx.x & 63;
    const int wid  = threadIdx.x >> 6;
    const int wm = wid >> 1, wn = wid & 1;
    const int r = lane & 15, g = lane >> 4;
#pragma unroll
    for (int ks = 0; ks < 2; ++ks) {
        bf16x8 af[2], bfr[4];
#pragma unroll
        for (int mt = 0; mt < 2; ++mt) {
            const int row = wm * 32 + mt * 16 + r;
            const int c8  = (ks * 4 + g) ^ (row & 7);
            af[mt] = *(const bf16x8*)(As + row * 64 + c8 * 8);
        }
#pragma unroll
        for (int nt = 0; nt < 4; ++nt) {
            const int row = wn * 64 + nt * 16 + r;
            const int c8  = (ks * 4 + g) ^ (row & 7);
            bfr[nt] = *(const bf16x8*)(Bs + row * 64 + c8 * 8);
        }
#pragma unroll
        for (int mt = 0; mt < 2; ++mt)
#pragma unroll
            for (int nt = 0; nt < 4; ++nt)
                acc[mt][nt] = mfma16(af[mt], bfr[nt], acc[mt][nt]);
    }
}

__device__ __forceinline__ void gemm_core(const bf16_t* __restrict__ A,
                                          const bf16_t* __restrict__ W,
                                          int m0, int n0,
                                          bf16_t (&As)[2][4096], bf16_t (&Bs)[2][8192],
                                          f32x4 (&acc)[2][4]) {
    stage_tile(A, W, m0, n0, 0, As[0], Bs[0]);
    asm volatile("s_waitcnt vmcnt(0)" ::: "memory");
    __builtin_amdgcn_s_barrier();
#pragma unroll
    for (int kt = 0; kt < 4; ++kt) {
        const int cur = kt & 1;
        if (kt < 3) stage_tile(A, W, m0, n0, kt + 1, As[cur ^ 1], Bs[cur ^ 1]);
        compute_tile(As[cur], Bs[cur], acc);
        if (kt < 3) {
            asm volatile("s_waitcnt vmcnt(0)" ::: "memory");
            __builtin_amdgcn_s_barrier();
        }
    }
}

// Fused QKV GEMM: Wp packed [768][256]. Grid (M/64, 6).
__global__ __launch_bounds__(256) void gemm_qkv(const bf16_t* __restrict__ A,
                                                const bf16_t* __restrict__ Wp,
                                                const float* __restrict__ bq,
                                                const float* __restrict__ bk,
                                                const float* __restrict__ bv,
                                                bf16_t* __restrict__ Qb,
                                                bf16_t* __restrict__ Kb,
                                                bf16_t* __restrict__ Vt) {
    __shared__ bf16_t As[2][4096], Bs[2][8192];
    f32x4 acc[2][4] = {};
    const int m0 = blockIdx.x * 64, n0 = blockIdx.y * 128;
    gemm_core(A, Wp, m0, n0, As, Bs, acc);
    const int lane = threadIdx.x & 63, wid = threadIdx.x >> 6;
    const int wm = wid >> 1, wn = wid & 1, r = lane & 15, g = lane >> 4;
#pragma unroll
    for (int nt = 0; nt < 4; ++nt) {
        const int col = n0 + wn * 64 + nt * 16 + r;
        const int t = col >> 8, cc = col & 255;
        const float bias = (t == 0 ? bq : t == 1 ? bk : bv)[cc];
#pragma unroll
        for (int mt = 0; mt < 2; ++mt)
#pragma unroll
            for (int rr = 0; rr < 4; ++rr) {
                const int row = m0 + wm * 32 + mt * 16 + g * 4 + rr;
                const float v = acc[mt][nt][rr] + bias;
                if (t == 0)      Qb[(size_t)row * D_HID + cc] = (bf16_t)v;
                else if (t == 1) Kb[(size_t)row * D_HID + cc] = (bf16_t)v;
                else             Vt[((size_t)(row >> 9) * D_HID + cc) * S_LEN + (row & 511)] = (bf16_t)v;
            }
    }
}

// Generic GEMM, N=256. EPI 1: gelu->bf16  2: f32  3: addsrc+ -> f32
template <int EPI>
__global__ __launch_bounds__(256) void gemm_one(const bf16_t* __restrict__ A,
                                                const bf16_t* __restrict__ W,
                                                const float* __restrict__ bias,
                                                void* __restrict__ outp,
                                                const float* __restrict__ addsrc) {
    __shared__ bf16_t As[2][4096], Bs[2][8192];
    f32x4 acc[2][4] = {};
    const int m0 = blockIdx.x * 64, n0 = blockIdx.y * 128;
    gemm_core(A, W, m0, n0, As, Bs, acc);
    const int lane = threadIdx.x & 63, wid = threadIdx.x >> 6;
    const int wm = wid >> 1, wn = wid & 1, r = lane & 15, g = lane >> 4;
#pragma unroll
    for (int nt = 0; nt < 4; ++nt) {
        const int col = n0 + wn * 64 + nt * 16 + r;
        const float bv = bias[col];
#pragma unroll
        for (int mt = 0; mt < 2; ++mt)
#pragma unroll
            for (int rr = 0; rr < 4; ++rr) {
                const size_t idx = (size_t)(m0 + wm * 32 + mt * 16 + g * 4 + rr) * D_HID + col;
                float v = acc[mt][nt][rr] + bv;
                if constexpr (EPI == 1) {
                    v = 0.5f * v * (1.f + erff(v * 0.70710678118654752f));
                    ((bf16_t*)outp)[idx] = (bf16_t)v;
                } else if constexpr (EPI == 2) {
                    ((float*)outp)[idx] = v;
                } else {
                    ((float*)outp)[idx] = addsrc[idx] + v;
                }
            }
    }
}

// ---------------------------------------------------------------------------
// Flash attention v8: BARRIER-FREE main loop. Grid 512 (XCD-chunked), 4 waves,
// each wave owns 16 q-rows and iterates ALL 512 keys (64/iter). Swapped QK^T,
// per-lane softmax (+2 shfl_xor over g), wave-private P_lds (same-wave
// write->read, no barrier), PV into O^T regs (64 VGPR). One barrier at the
// epilogue for the O transpose. Waves run fully decoupled.
// ---------------------------------------------------------------------------
__global__ __launch_bounds__(256, 2) void attn_fwd(const bf16_t* __restrict__ Q,
                                                   const bf16_t* __restrict__ K,
                                                   const bf16_t* __restrict__ Vt,
                                                   const float* __restrict__ btab,
                                                   const int* __restrict__ mask,
                                                   bf16_t* __restrict__ AO) {
    __shared__ float  bias_lds[1024];
    __shared__ float  mask_add[512];
    __shared__ bf16_t P_all[4][16 * 64];     // 2KB per wave, 128B rows, swizzled
    __shared__ bf16_t o_lds[64][264];        // 33.7KB

    const int tid = threadIdx.x, lane = tid & 63, w = tid >> 6;
    const int r = lane & 15, g = lane >> 4;

    // XCD-chunked mapping: 8 batches per XCD; adjacent blocks share a batch
    const int lid = blockIdx.x;
    const int xcd = lid & 7, slot = lid >> 3;          // slot 0..63
    const int b  = xcd * 8 + (slot >> 3);
    const int q0 = (slot & 7) * 64;

    for (int i = tid; i < 1024; i += 256) {
        const int rel = i - 512;
        const int bucket = (rel < 0) ? (511 - rel) : rel;
        bias_lds[i] = btab[bucket];
    }
    for (int i = tid; i < 512; i += 256)
        mask_add[i] = mask[b * S_LEN + i] ? 0.f : -3.0e38f;
    __syncthreads();

    const int qbase = q0 + w * 16;
    const bf16_t* Qp = Q  + ((size_t)b * S_LEN + qbase) * D_HID;
    const bf16_t* Kp = K  + (size_t)b * S_LEN * D_HID;
    const bf16_t* Vp = Vt + (size_t)b * D_HID * S_LEN;
    char* pst = (char*)&P_all[w][0];
    const int qg = qbase + r;

    // Q-hoist: wave's 16 q-rows, all K-slices (32 VGPR)
    bf16x8 qf[8];
#pragma unroll
    for (int ks = 0; ks < 8; ++ks)
        qf[ks] = *(const bf16x8*)(Qp + (size_t)r * D_HID + ks * 32 + g * 8);

    f32x4 oacc[16] = {};                     // O^T: all 256 d x 16 q
    float m_run = -3.0e38f, l_run = 0.f;

#pragma unroll 1
    for (int kt = 0; kt < 8; ++kt) {
        const int k0 = kt * 64;
        // ---- QK^T: 4 sub-tiles of 16 keys, 4 independent chains
        f32x4 sacc[4] = {};
#pragma unroll
        for (int ks = 0; ks < 8; ++ks) {
            bf16x8 kf[4];
#pragma unroll
            for (int tt = 0; tt < 4; ++tt)
                kf[tt] = *(const bf16x8*)(Kp + (size_t)(k0 + tt * 16 + r) * D_HID
                                               + ks * 32 + g * 8);
            __builtin_amdgcn_s_setprio(1);
#pragma unroll
            for (int tt = 0; tt < 4; ++tt)
                sacc[tt] = mfma16(kf[tt], qf[ks], sacc[tt]);
            __builtin_amdgcn_s_setprio(0);
        }
        // ---- softmax over the 64 new keys (per-lane 16 values + g-reduce)
        float mx = -3.0e38f;
#pragma unroll
        for (int tt = 0; tt < 4; ++tt)
#pragma unroll
            for (int rr = 0; rr < 4; ++rr) {
                const int kg = k0 + tt * 16 + g * 4 + rr;
                float ev = sacc[tt][rr] * 0.0625f + bias_lds[kg - qg + 512] + mask_add[kg];
                sacc[tt][rr] = ev;
                mx = fmaxf(mx, ev);
            }
        mx = fmaxf(mx, __shfl_xor(mx, 16));
        mx = fmaxf(mx, __shfl_xor(mx, 32));
        const float mnew = fmaxf(m_run, mx);
        const float fac  = __expf(m_run - mnew);
        m_run = mnew;
        // ---- P = exp, l-partials, pack bf16 -> wave-private swizzled LDS
        float ls = 0.f;
#pragma unroll
        for (int tt = 0; tt < 4; ++tt) {
            const float p0 = __expf(sacc[tt][0] - mnew);
            const float p1 = __expf(sacc[tt][1] - mnew);
            const float p2 = __expf(sacc[tt][2] - mnew);
            const float p3 = __expf(sacc[tt][3] - mnew);
            ls += (p0 + p1) + (p2 + p3);
            const int u = (2 * tt + (g >> 1)) ^ (r & 7);   // 16B-unit XOR swizzle
            uint2 pv; pv.x = pk_bf16(p0, p1); pv.y = pk_bf16(p2, p3);
            *(uint2*)(pst + r * 128 + u * 16 + (g & 1) * 8) = pv;
        }
        ls += __shfl_xor(ls, 16);
        ls += __shfl_xor(ls, 32);
        l_run = l_run * fac + ls;
        // ---- O rescale (lane's q = r, fac is per-lane scalar)
#pragma unroll
        for (int nt = 0; nt < 16; ++nt)
#pragma unroll
            for (int rr = 0; rr < 4; ++rr)
                oacc[nt][rr] *= fac;
        // ---- PV: A = Vt d-rows (contiguous 16B), B = P rows (swizzled LDS)
#pragma unroll
        for (int ks2 = 0; ks2 < 2; ++ks2) {
            const int u = (ks2 * 4 + g) ^ (r & 7);
            bf16x8 pf = *(const bf16x8*)(pst + r * 128 + u * 16);
            __builtin_amdgcn_s_setprio(1);
#pragma unroll
            for (int nt = 0; nt < 16; ++nt) {
                bf16x8 vf = *(const bf16x8*)(Vp + (size_t)(nt * 16 + r) * S_LEN
                                                  + k0 + ks2 * 32 + g * 8);
                oacc[nt] = mfma16(vf, pf, oacc[nt]);
            }
            __builtin_amdgcn_s_setprio(0);
        }
    }
    // ---- epilogue: scale 1/l, transpose via LDS (one barrier), store
    const float inv_l = 1.f / fmaxf(l_run, 1e-30f);
#pragma unroll
    for (int nt = 0; nt < 16; ++nt) {
        const int d = nt * 16 + g * 4;
        bf16x4 ob = { (bf16_t)(oacc[nt][0] * inv_l),
                      (bf16_t)(oacc[nt][1] * inv_l),
                      (bf16_t)(oacc[nt][2] * inv_l),
                      (bf16_t)(oacc[nt][3] * inv_l) };
        *(bf16x4*)&o_lds[w * 16 + r][d] = ob;
    }
    __syncthreads();
    bf16_t* Op = AO + ((size_t)b * S_LEN + q0) * D_HID;
#pragma unroll
    for (int it = 0; it < 8; ++it) {
        const int idx = it * 256 + tid;      // 2048 units = 64 rows x 32 x 16B
        const int row = idx >> 5, u = idx & 31;
        bf16x8 vv = *(const bf16x8*)&o_lds[row][u * 8];
        *(bf16x8*)(Op + (size_t)row * D_HID + u * 8) = vv;
    }
}

// ---------------------------------------------------------------------------
extern "C" void kernel_launch(void* const* d_in, const int* in_sizes, int n_in,
                              void* d_out, int out_size, void* d_ws, size_t ws_size,
                              hipStream_t stream) {
    const float* x_in = (const float*)d_in[0];
    const int*   mask = (const int*)d_in[1];
    const float* btab = (const float*)d_in[2];
    const float* ln_g = (const float*)d_in[3];
    const float* ln_b = (const float*)d_in[4];
    const float* wq = (const float*)d_in[5];
    const float* bq = (const float*)d_in[6];
    const float* wk = (const float*)d_in[7];
    const float* bk = (const float*)d_in[8];
    const float* wv = (const float*)d_in[9];
    const float* bv = (const float*)d_in[10];
    const float* wo = (const float*)d_in[11];
    const float* bo = (const float*)d_in[12];
    const float* cg = (const float*)d_in[13];
    const float* cb = (const float*)d_in[14];
    const float* w1 = (const float*)d_in[15];
    const float* b1 = (const float*)d_in[16];
    const float* w2 = (const float*)d_in[17];
    const float* b2 = (const float*)d_in[18];
    float* out = (float*)d_out;

    // Workspace layout (~120 MB). AO has its OWN region (round-6 lesson).
    char* p = (char*)d_ws;
    const size_t F32SZ  = (size_t)M_ROWS * D_HID * sizeof(float);   // 33.5 MB
    const size_t BF16SZ = (size_t)M_ROWS * D_HID * sizeof(bf16_t);  // 16.8 MB
    float*  X  = (float*)p;  p += F32SZ;
    bf16_t* Hb = (bf16_t*)p; p += BF16SZ;   // residual h (bf16), live thru ln_res_ln
    bf16_t* Qb = (bf16_t*)p; p += BF16SZ;   // later: Cb
    bf16_t* Kb = (bf16_t*)p;                // T (f32) spans Kb+Vt; T1b reuses Kb
    float*  T  = (float*)Kb;
    bf16_t* T1b = Kb;
    p += BF16SZ;
    bf16_t* Vt = (bf16_t*)p; p += BF16SZ;   // transposed V [b][d][s]
    bf16_t* AO = (bf16_t*)p; p += BF16SZ;   // attention output (separate!)
    bf16_t* Wqkv = (bf16_t*)p; p += (size_t)N_L * 768 * 256 * sizeof(bf16_t);  // packed
    bf16_t* Wrest = (bf16_t*)p;             // Wo,W1,W2: 3 * L * 65536 bf16
    bf16_t* Cb = Qb;

    transpose_all<<<dim3(768, 6), dim3(256), 0, stream>>>(wq, wk, wv, wo, w1, w2, Wqkv, Wrest);

    const dim3 gblk(256, 1, 1);
    const dim3 grid_qkv(M_ROWS / 64, 6, 1);
    const dim3 grid_one(M_ROWS / 64, 2, 1);

    for (int j = 0; j < N_L; ++j) {
        const bf16_t* WQKVj = Wqkv + (size_t)j * 3 * 65536;
        const bf16_t* WOt = Wrest + ((size_t)0 * N_L + j) * 65536;
        const bf16_t* W1t = Wrest + ((size_t)1 * N_L + j) * 65536;
        const bf16_t* W2t = Wrest + ((size_t)2 * N_L + j) * 65536;

        ln_fwd<<<dim3(M_ROWS / 4), gblk, 0, stream>>>(j == 0 ? x_in : X,
                                                      ln_g + j * D_HID, ln_b + j * D_HID, Hb);
        gemm_qkv<<<grid_qkv, gblk, 0, stream>>>(Hb, WQKVj, bq + j * D_HID, bk + j * D_HID,
                                                bv + j * D_HID, Qb, Kb, Vt);
        attn_fwd<<<dim3(512, 1, 1), gblk, 0, stream>>>(Qb, Kb, Vt, btab, mask, AO);
        gemm_one<2><<<grid_one, gblk, 0, stream>>>(AO, WOt, bo + j * D_HID, T, nullptr);
        ln_res_ln<<<dim3(M_ROWS / 4), gblk, 0, stream>>>(T, Hb, ln_g + j * D_HID, ln_b + j * D_HID,
                                                         cg + j * D_HID, cb + j * D_HID, X, Cb);
        gemm_one<1><<<grid_one, gblk, 0, stream>>>(Cb, W1t, b1 + j * D_HID, T1b, nullptr);
        gemm_one<3><<<grid_one, gblk, 0, stream>>>(T1b, W2t, b2 + j * D_HID,
                                                   (j == N_L - 1) ? (void*)out : (void*)X, X);
    }
}